// Round 8
// baseline (510.345 us; speedup 1.0000x reference)
//
#include <hip/hip_runtime.h>
#include <math.h>

#define N_TOK 32768
#define K_CODES 4096
#define DIM 512
#define COMMIT 0.25f
#define NCAND 8
#define NSPLIT 2
#define SPLIT_CODES (K_CODES / NSPLIT)   // 2048
#define NITER (SPLIT_CODES / 256)        // 8 col-iterations of 256 codes
#define BIAS 0.125f

typedef short s16x8 __attribute__((ext_vector_type(8)));
typedef float f32x4 __attribute__((ext_vector_type(4)));
typedef unsigned int uint32;
typedef unsigned long long u64;
typedef unsigned short u16;

__device__ __forceinline__ u16 f2bf(float f) {
    uint32 b = __float_as_uint(f);
    return (u16)((b + 0x7FFFu + ((b >> 16) & 1u)) >> 16);
}

// global -> LDS direct DMA, 16B per lane. LDS dest wave-uniform; HW writes
// lds + lane*16. Source address is per-lane (pre-swizzled).
__device__ __forceinline__ void gload16(const u16* g, u16* l) {
    __builtin_amdgcn_global_load_lds(
        (const __attribute__((address_space(1))) void*)g,
        (__attribute__((address_space(3))) void*)l,
        16, 0, 0);
}

// ---------------------------------------------------------------------------
// fp32 -> bf16 (RNE) bulk convert.
// ---------------------------------------------------------------------------
__global__ __launch_bounds__(256) void tobf16_kernel(const float* __restrict__ src,
                                                     u16* __restrict__ dst, int n4) {
    int i = blockIdx.x * 256 + threadIdx.x;
    int stride = gridDim.x * 256;
    for (; i < n4; i += stride) {
        float4 v = ((const float4*)src)[i];
        ushort4 o;
        o.x = f2bf(v.x); o.y = f2bf(v.y); o.z = f2bf(v.z); o.w = f2bf(v.w);
        ((ushort4*)dst)[i] = o;
    }
}

// ---------------------------------------------------------------------------
// numpy-exact fp32 row sum of squares (pairwise algorithm) — R3-verified.
// ---------------------------------------------------------------------------
__global__ __launch_bounds__(256) void rowsq_np_kernel(const float* __restrict__ a,
                                                       float* __restrict__ out,
                                                       int nrows) {
    #pragma clang fp contract(off)
    const int gw   = (blockIdx.x * 256 + threadIdx.x) >> 6;
    const int lane = threadIdx.x & 63;
    const int row  = gw * 8 + (lane >> 3);
    const int j    = lane & 7;
    if (row >= nrows) return;
    const float* p = a + (size_t)row * DIM;
    float blk[4];
    #pragma unroll
    for (int b = 0; b < 4; ++b) {
        const float* q = p + b * 128;
        float v = q[j];
        float r = v * v;
        for (int i = 8; i < 128; i += 8) { float u = q[i + j]; r += u * u; }
        float s1 = r  + __shfl_xor(r, 1);
        float s2 = s1 + __shfl_xor(s1, 2);
        float s3 = s2 + __shfl_xor(s2, 4);
        blk[b] = s3;
    }
    float res = (blk[0] + blk[1]) + (blk[2] + blk[3]);
    if (j == 0) out[row] = res;
}

// ---------------------------------------------------------------------------
// MFMA bf16 screen — FAT TILE for staging-intensity (R2/R4/R6 established
// time ≈ staged-bytes / ~35 GB/s/CU; only FLOP-per-staged-byte moves it).
// Block: 512 thr = 8 waves, tile 256 tok x 256 codes/iter (NITER=8).
// Wave tile 64 tok x 128 codes (4x8 grid of 16x16x32 MFMA, acc[4][8]=128
// VGPR). BK=64 chunks, double-buffered LDS: X 2x32K + W 2x32K = 128 KiB ->
// 1 block/CU, 2 waves/SIMD -> 256-VGPR budget is free (launch_bounds(512,2)).
// 131 FLOP per staged byte vs 87 in R2 (+50%). Grid 256 blocks = 1/CU exact.
// 128B LDS rows, XOR-swizzled 16B quanta (R2-verified conflict-free);
// DMA = linear LDS dest + pre-swizzled source quantum (lane&7)^(lane>>3).
// Screening: top-2 per 64-code bucket (8 cf-frags folded per (lane,ti)),
// id=(it<<3)|cf (6 bits), 64 entries/token -> top-6 per split, NCAND=8.
// ---------------------------------------------------------------------------
__global__ __launch_bounds__(512, 2) void screen_kernel(const u16* __restrict__ xb,
                                                        const u16* __restrict__ wb,
                                                        const float* __restrict__ w2f,
                                                        u64* __restrict__ candPart) {
    __shared__ __attribute__((aligned(16))) u16 POOL[65536];  // 128 KiB
    // u16 units: X0 @0, X1 @16384, W0 @32768, W1 @49152 (each 256 rows x 64).
    // Merge phase reuses ALL 128 KiB as 256 tok x 64 u64.

    const int tid  = threadIdx.x;
    const int wv   = tid >> 6;
    const int wt   = wv >> 1;          // token quarter (0..3), 64 rows each
    const int wcc  = wv & 1;           // code half (0/1), 128 codes each
    const int lane = tid & 63;
    const int quad = lane >> 4;
    const int n15  = lane & 15;
    const int m0   = blockIdx.x * 256;
    const int sbase = blockIdx.y * SPLIT_CODES;

    // DMA geometry: 1 instr = 64 lanes x 16B = 8 rows x 8 quanta (128B rows).
    // phys quantum p at row r holds logical p^(r&7); r&7 == lane>>3 for
    // 8-aligned row bases -> src quantum = (lane&7)^(lane>>3).
    const int l8  = lane >> 3;
    const int qsw = (lane & 7) ^ l8;

    // X: 256 rows, 32 per wave -> 4 instrs (j*8 rows each).
    const u16* xg = xb + (size_t)(m0 + wv * 32 + l8) * DIM + qsw * 8;
    // W: 256 rows/chunk, 32 per wave -> 4 instrs; per-it base advances 256 rows.
    const u16* wit = wb + (size_t)(sbase + wv * 32 + l8) * DIM + qsw * 8;

    uint32 r1[16], r2[16];
    #pragma unroll
    for (int i = 0; i < 16; ++i) { r1[i] = 0xFFFFFFFFu; r2[i] = 0xFFFFFFFFu; }

    // prologue: stage it=0 chunk 0 into buffer 0
    #pragma unroll
    for (int j = 0; j < 4; ++j) {
        gload16(xg + (size_t)(j * 8) * DIM, &POOL[wv * 2048 + j * 512]);
        gload16(wit + (size_t)(j * 8) * DIM, &POOL[32768 + wv * 2048 + j * 512]);
    }
    __syncthreads();

    for (int it = 0; it < NITER; ++it) {
        const int nbase = sbase + it * 256;

        float w2pb[8];
        #pragma unroll
        for (int c = 0; c < 8; ++c) w2pb[c] = w2f[nbase + wcc * 128 + c * 16 + n15] + BIAS;

        f32x4 acc[4][8];
        #pragma unroll
        for (int i = 0; i < 4; ++i)
            #pragma unroll
            for (int c = 0; c < 8; ++c) acc[i][c] = (f32x4){0.f, 0.f, 0.f, 0.f};

        for (int kc = 0; kc < 8; ++kc) {
            // prefetch chunk kc+1 of this column, or chunk 0 of next column
            if (kc < 7) {
                const int nb = (kc + 1) & 1;
                const int ko = (kc + 1) * 64;
                #pragma unroll
                for (int j = 0; j < 4; ++j) {
                    gload16(xg + (size_t)(j * 8) * DIM + ko,
                            &POOL[nb * 16384 + wv * 2048 + j * 512]);
                    gload16(wit + (size_t)(j * 8) * DIM + ko,
                            &POOL[32768 + nb * 16384 + wv * 2048 + j * 512]);
                }
            } else if (it < NITER - 1) {
                const u16* wn = wit + (size_t)256 * DIM;
                #pragma unroll
                for (int j = 0; j < 4; ++j) {
                    gload16(xg + (size_t)(j * 8) * DIM, &POOL[wv * 2048 + j * 512]);
                    gload16(wn + (size_t)(j * 8) * DIM, &POOL[32768 + wv * 2048 + j * 512]);
                }
            }

            const u16* X = &POOL[(kc & 1) * 16384];
            const u16* W = &POOL[32768 + (kc & 1) * 16384];
            #pragma unroll
            for (int s = 0; s < 2; ++s) {
                const int qoff = ((s * 4 + quad) ^ (n15 & 7)) * 8;
                s16x8 af[4];
                #pragma unroll
                for (int i = 0; i < 4; ++i) {
                    const int tr = wt * 64 + i * 16 + n15;      // tr&7 == n15&7
                    af[i] = *(const s16x8*)&X[tr * 64 + qoff];
                }
                #pragma unroll
                for (int c = 0; c < 8; ++c) {
                    const int cr = wcc * 128 + c * 16 + n15;    // cr&7 == n15&7
                    s16x8 bf = *(const s16x8*)&W[cr * 64 + qoff];
                    #pragma unroll
                    for (int i = 0; i < 4; ++i)
                        acc[i][c] = __builtin_amdgcn_mfma_f32_16x16x32_bf16(af[i], bf, acc[i][c], 0, 0, 0);
                }
            }
            __syncthreads();   // drain -> staged chunk visible
        }

        // fold this 256-code column into running top-2 per (lane, token-slot)
        #pragma unroll
        for (int i = 0; i < 4; ++i)
            #pragma unroll
            for (int r = 0; r < 4; ++r) {
                const int ti = i * 4 + r;
                #pragma unroll
                for (int c = 0; c < 8; ++c) {
                    float s = fmaf(-2.0f, acc[i][c][r], w2pb[c]);
                    uint32 key = (__float_as_uint(s) & 0xFFFFFFC0u) | (uint32)((it << 3) | c);
                    uint32 mx = r1[ti] > key ? r1[ti] : key;
                    r1[ti] = r1[ti] < key ? r1[ti] : key;
                    r2[ti] = r2[ti] < mx ? r2[ti] : mx;
                }
            }
        wit += (size_t)256 * DIM;
    }

    // ------- merge: 256 tokens x 64 entries via LDS (128 KiB), one phase ----
    // All waves passed the final kc-barrier (all LDS reads done); MS writes
    // are disjoint slots; one barrier before the reduction.
    u64* MS = (u64*)POOL;   // 256 tokens x 64 entries = 128 KiB exactly
    #pragma unroll
    for (int ti = 0; ti < 16; ++ti) {
        const int i = ti >> 2, r = ti & 3;
        const int tloc = wt * 64 + i * 16 + quad * 4 + r;    // 0..255
        #pragma unroll
        for (int e = 0; e < 2; ++e) {
            uint32 k  = e ? r2[ti] : r1[ti];
            uint32 vb = k & 0xFFFFFFC0u;
            uint32 id = k & 63u;
            uint32 code = (uint32)(sbase + (id >> 3) * 256 + wcc * 128 + (id & 7) * 16 + n15);
            MS[tloc * 64 + (wcc * 16 + n15) * 2 + e] = ((u64)vb << 32) | code;
        }
    }
    __syncthreads();
    if (tid < 256) {
        u64 best[6];
        #pragma unroll
        for (int c = 0; c < 6; ++c) best[c] = 0xFFFFFFFFFFFFFFFFull;
        for (int e = 0; e < 64; ++e) {
            u64 v = MS[tid * 64 + e];
            if (v < best[5]) {
                best[5] = v;
                #pragma unroll
                for (int p = 5; p > 0; --p)
                    if (best[p] < best[p - 1]) { u64 tv = best[p]; best[p] = best[p - 1]; best[p - 1] = tv; }
            }
        }
        const int token = m0 + tid;
        u64* dst = candPart + ((size_t)blockIdx.y * N_TOK + token) * 6;
        #pragma unroll
        for (int c = 0; c < 6; ++c) dst[c] = best[c];
    }
}

// ---------------------------------------------------------------------------
// Merge per-split top-6 lists -> global top-NCAND candidate codes per token.
// ---------------------------------------------------------------------------
__global__ __launch_bounds__(256) void mergecand_kernel(const u64* __restrict__ candPart,
                                                        int* __restrict__ candF) {
    int t = blockIdx.x * 256 + threadIdx.x;
    u64 best[NCAND];
    #pragma unroll
    for (int c = 0; c < NCAND; ++c) best[c] = 0xFFFFFFFFFFFFFFFFull;
    for (int s = 0; s < NSPLIT; ++s) {
        const u64* src = candPart + ((size_t)s * N_TOK + t) * 6;
        #pragma unroll
        for (int c = 0; c < 6; ++c) {
            u64 v = src[c];
            if (v < best[NCAND - 1]) {
                best[NCAND - 1] = v;
                #pragma unroll
                for (int p = NCAND - 1; p > 0; --p)
                    if (best[p] < best[p - 1]) { u64 tv = best[p]; best[p] = best[p - 1]; best[p - 1] = tv; }
            }
        }
    }
    #pragma unroll
    for (int c = 0; c < NCAND; ++c) candF[(size_t)t * NCAND + c] = (int)(best[c] & 0xFFFu);
}

// ---------------------------------------------------------------------------
// np-exact refine over NCAND candidates (R3-verified arithmetic).
// ---------------------------------------------------------------------------
__global__ __launch_bounds__(256) void refine_kernel(const float* __restrict__ x,
                                                     const float* __restrict__ w,
                                                     const float* __restrict__ x2np,
                                                     const float* __restrict__ w2np,
                                                     const int* __restrict__ cand,
                                                     int* __restrict__ idx) {
    const int t    = blockIdx.x * 4 + (threadIdx.x >> 6);
    const int lane = threadIdx.x & 63;

    const float* xr = x + (size_t)t * DIM;
    float xv[8];
    #pragma unroll
    for (int j = 0; j < 8; ++j) xv[j] = xr[lane + 64 * j];
    const float x2 = x2np[t];

    float bd = 3.4e38f;
    int   bk = 0x7fffffff;
    for (int c = 0; c < NCAND; ++c) {
        int k = cand[(size_t)t * NCAND + c];
        const float* wr = w + (size_t)k * DIM;
        double m = 0.0;
        #pragma unroll
        for (int j = 0; j < 8; ++j)
            m = fma((double)xv[j], (double)wr[lane + 64 * j], m);
        #pragma unroll
        for (int off = 32; off >= 1; off >>= 1) m += __shfl_down(m, off);
        if (lane == 0) {
            #pragma clang fp contract(off)
            float m32 = (float)m;
            float T1  = x2 + w2np[k];
            float d   = T1 - 2.0f * m32;
            if (d < bd || (d == bd && k < bk)) { bd = d; bk = k; }
        }
    }
    if (lane == 0) idx[t] = bk;
}

// ---------------------------------------------------------------------------
// gather + straight-through output + loss + counts (R3-verified).
// ---------------------------------------------------------------------------
__global__ __launch_bounds__(256) void gather_kernel(const float* __restrict__ x,
                                                     const float* __restrict__ w,
                                                     const int* __restrict__ idx,
                                                     float* __restrict__ out_q,
                                                     float* __restrict__ out_loss,
                                                     float* __restrict__ out_ind,
                                                     int* __restrict__ counts) {
    const int wave = threadIdx.x >> 6;
    const int lane = threadIdx.x & 63;
    const int token = blockIdx.x * 4 + wave;
    const int k = idx[token];

    const float4* xr = (const float4*)(x + (size_t)token * DIM);
    const float4* wr = (const float4*)(w + (size_t)k * DIM);
    float4*       qo = (float4*)(out_q + (size_t)token * DIM);

    float ss = 0.f;
    #pragma unroll
    for (int j = 0; j < 2; ++j) {
        int e = lane + j * 64;
        float4 xv = xr[e];
        float4 wv = wr[e];
        float4 d, o;
        d.x = wv.x - xv.x; o.x = xv.x + d.x;
        d.y = wv.y - xv.y; o.y = xv.y + d.y;
        d.z = wv.z - xv.z; o.z = xv.z + d.z;
        d.w = wv.w - xv.w; o.w = xv.w + d.w;
        ss += d.x * d.x + d.y * d.y + d.z * d.z + d.w * d.w;
        qo[e] = o;
    }
    #pragma unroll
    for (int off = 32; off >= 1; off >>= 1) ss += __shfl_down(ss, off);
    if (lane == 0) {
        float lm = ss * (1.0f / DIM);
        out_loss[token] = lm + COMMIT * lm;
        out_ind[token] = (float)k;
        atomicAdd(&counts[k], 1);
    }
}

// ---------------------------------------------------------------------------
// perplexity (R3-verified).
// ---------------------------------------------------------------------------
__global__ __launch_bounds__(256) void perplex_kernel(const int* __restrict__ counts,
                                                      float* __restrict__ out2) {
    __shared__ double red[4];
    const int tid = threadIdx.x;
    const int lane = tid & 63;
    const int wid = tid >> 6;
    double s = 0.0;
    for (int t = tid; t < K_CODES; t += 256) {
        int c = counts[t];
        if (c) {
            double p = (double)c * (1.0 / N_TOK);
            s += p * log(p + 1e-10);
        }
    }
    #pragma unroll
    for (int off = 32; off >= 1; off >>= 1) s += __shfl_down(s, off);
    if (lane == 0) red[wid] = s;
    __syncthreads();
    if (tid == 0) {
        double t = red[0] + red[1] + red[2] + red[3];
        out2[0] = (float)exp(-t);
    }
}

// ---------------------------------------------------------------------------
extern "C" void kernel_launch(void* const* d_in, const int* in_sizes, int n_in,
                              void* d_out, int out_size, void* d_ws, size_t ws_size,
                              hipStream_t stream) {
    const float* x = (const float*)d_in[0];
    const float* w = (const float*)d_in[1];

    float* out0 = (float*)d_out;                       // quantized_st [N,D]
    float* out1 = out0 + (size_t)N_TOK * DIM;          // loss [N]
    float* out2 = out1 + N_TOK;                        // perplexity [1]
    float* out3 = out2 + 1;                            // indices [N] (as float)

    // workspace layout (8B-aligned chunks first)
    u64*   candPart = (u64*)d_ws;                                 // NSPLIT*N_TOK*6
    float* x2np     = (float*)(candPart + (size_t)NSPLIT * N_TOK * 6);
    float* w2np     = x2np + N_TOK;
    int*   idx      = (int*)(w2np + K_CODES);
    int*   counts   = idx + N_TOK;
    int*   candF    = counts + K_CODES;                           // N_TOK*NCAND
    u16*   x_bf     = (u16*)(candF + (size_t)N_TOK * NCAND);      // N_TOK*DIM
    u16*   w_bf     = x_bf + (size_t)N_TOK * DIM;                 // K_CODES*DIM

    hipMemsetAsync(counts, 0, K_CODES * sizeof(int), stream);

    tobf16_kernel<<<4096, 256, 0, stream>>>(x, x_bf, N_TOK * DIM / 4);
    tobf16_kernel<<<2048, 256, 0, stream>>>(w, w_bf, K_CODES * DIM / 4);
    rowsq_np_kernel<<<N_TOK / 32, 256, 0, stream>>>(x, x2np, N_TOK);
    rowsq_np_kernel<<<K_CODES / 32, 256, 0, stream>>>(w, w2np, K_CODES);
    screen_kernel<<<dim3(N_TOK / 256, NSPLIT), 512, 0, stream>>>(x_bf, w_bf, w2np, candPart);
    mergecand_kernel<<<N_TOK / 256, 256, 0, stream>>>(candPart, candF);
    refine_kernel<<<N_TOK / 4, 256, 0, stream>>>(x, w, x2np, w2np, candF, idx);
    gather_kernel<<<N_TOK / 4, 256, 0, stream>>>(x, w, idx, out0, out1, out3, counts);
    perplex_kernel<<<1, 256, 0, stream>>>(counts, out2);
}

// Round 9
// 446.933 us; speedup vs baseline: 1.1419x; 1.1419x over previous
//
#include <hip/hip_runtime.h>
#include <math.h>

#define N_TOK 32768
#define K_CODES 4096
#define DIM 512
#define COMMIT 0.25f
#define NCAND 8
#define NSPLIT 2
#define SPLIT_CODES (K_CODES / NSPLIT)   // 2048
#define NITER (SPLIT_CODES / 256)        // 8 col-iterations of 256 codes
#define BIAS 0.125f

typedef short s16x8 __attribute__((ext_vector_type(8)));
typedef float f32x4 __attribute__((ext_vector_type(4)));
typedef unsigned int uint32;
typedef unsigned long long u64;
typedef unsigned short u16;

__device__ __forceinline__ u16 f2bf(float f) {
    uint32 b = __float_as_uint(f);
    return (u16)((b + 0x7FFFu + ((b >> 16) & 1u)) >> 16);
}

// global -> LDS direct DMA, 16B per lane. LDS dest wave-uniform; HW writes
// lds + lane*16. Source address is per-lane (pre-swizzled).
__device__ __forceinline__ void gload16(const u16* g, u16* l) {
    __builtin_amdgcn_global_load_lds(
        (const __attribute__((address_space(1))) void*)g,
        (__attribute__((address_space(3))) void*)l,
        16, 0, 0);
}

// ---------------------------------------------------------------------------
// fp32 -> bf16 (RNE) bulk convert.
// ---------------------------------------------------------------------------
__global__ __launch_bounds__(256) void tobf16_kernel(const float* __restrict__ src,
                                                     u16* __restrict__ dst, int n4) {
    int i = blockIdx.x * 256 + threadIdx.x;
    int stride = gridDim.x * 256;
    for (; i < n4; i += stride) {
        float4 v = ((const float4*)src)[i];
        ushort4 o;
        o.x = f2bf(v.x); o.y = f2bf(v.y); o.z = f2bf(v.z); o.w = f2bf(v.w);
        ((ushort4*)dst)[i] = o;
    }
}

// ---------------------------------------------------------------------------
// numpy-exact fp32 row sum of squares (pairwise algorithm) — R3-verified.
// ---------------------------------------------------------------------------
__global__ __launch_bounds__(256) void rowsq_np_kernel(const float* __restrict__ a,
                                                       float* __restrict__ out,
                                                       int nrows) {
    #pragma clang fp contract(off)
    const int gw   = (blockIdx.x * 256 + threadIdx.x) >> 6;
    const int lane = threadIdx.x & 63;
    const int row  = gw * 8 + (lane >> 3);
    const int j    = lane & 7;
    if (row >= nrows) return;
    const float* p = a + (size_t)row * DIM;
    float blk[4];
    #pragma unroll
    for (int b = 0; b < 4; ++b) {
        const float* q = p + b * 128;
        float v = q[j];
        float r = v * v;
        for (int i = 8; i < 128; i += 8) { float u = q[i + j]; r += u * u; }
        float s1 = r  + __shfl_xor(r, 1);
        float s2 = s1 + __shfl_xor(s1, 2);
        float s3 = s2 + __shfl_xor(s2, 4);
        blk[b] = s3;
    }
    float res = (blk[0] + blk[1]) + (blk[2] + blk[3]);
    if (j == 0) out[row] = res;
}

// ---------------------------------------------------------------------------
// MFMA bf16 screen — R2 geometry + R5 counted-vmcnt pipeline, spill-proofed.
// Block: 512 thr = 8 waves, tile 128 tok x 256 codes/iter (NITER=8).
// Wave tile 64 tok x 64 codes (4x4 MFMA grid, acc[4][4]=64 regs — the proven
// spill-free budget). K chunks BK=64, flat t=0..63. TRIPLE-buffered LDS:
// X 3x16K + W 3x32K + w2-table 8K = 152 KiB. Per chunk: s_waitcnt vmcnt(6)
// (never 0 until t=63) -> s_barrier -> sched_barrier -> issue chunk t+2 (6
// DMAs/wave) -> 32 MFMA on chunk t -> fold at it-end (w2 from LDS: lgkmcnt
// only, so vmcnt counting stays exact). Race safety proven by R5 (absmax 0):
// barrier certifies compute(t-1) done everywhere before DMA targets
// buf[(t+2)%3]==buf[(t-1)%3]. Spill traps removed vs R5: no outer-loop
// unroll, no register w2 array (w2 staged in LDS in prologue).
// 128B LDS rows, XOR-swizzled 16B quanta; DMA = linear LDS dest +
// pre-swizzled per-lane source quantum (lane&7)^(lane>>3).
// Screening semantics identical to R2-verified: top-2 per (lane,ti) 32-code
// bucket, id=(it<<2)|c, top-6 per token per split, NCAND=8 refine.
// ---------------------------------------------------------------------------
__global__ __launch_bounds__(512, 2) void screen_kernel(const u16* __restrict__ xb,
                                                        const u16* __restrict__ wb,
                                                        const float* __restrict__ w2f,
                                                        u64* __restrict__ candPart) {
    __shared__ __attribute__((aligned(16))) u16 POOL[77824];  // 152 KiB
    // u16 offsets: X bufs {0, 8192, 16384} (128 rows x 64 each),
    //              W bufs {24576, 40960, 57344} (256 rows x 64 each),
    //              w2 table @73728 (2048 floats = 8 KiB).
    // Merge phase reuses first 64 KiB as 64 tok x 128 u64.

    const int tid  = threadIdx.x;
    const int wv   = tid >> 6;
    const int wt   = wv >> 2;          // token half (0/1), 64 rows each
    const int wc   = wv & 3;           // code column (0..3), 64 codes each
    const int lane = tid & 63;
    const int quad = lane >> 4;
    const int n15  = lane & 15;
    const int m0   = blockIdx.x * 128;
    const int sbase = blockIdx.y * SPLIT_CODES;

    // DMA geometry: 1 instr = 64 lanes x 16B = 8 rows x 8 quanta (128B rows).
    // phys quantum p at row r holds logical p^(r&7); r&7 == lane>>3 for
    // 8-aligned row bases -> src quantum = (lane&7)^(lane>>3).
    const int l8  = lane >> 3;
    const int qsw = (lane & 7) ^ l8;

    // X: 128 rows, 16 per wave -> 2 instrs.
    const u16* xg0 = xb + (size_t)(m0 + wv * 16 + l8) * DIM + qsw * 8;
    const u16* xg1 = xg0 + (size_t)8 * DIM;
    // W: 256 rows/chunk, 32 per wave -> 4 instrs; chunk (it,kc) adds
    // it*256*DIM + kc*64.
    const u16* wg0 = wb + (size_t)(sbase + wv * 32 + 0  + l8) * DIM + qsw * 8;
    const u16* wg1 = wg0 + (size_t)8 * DIM;
    const u16* wg2 = wg0 + (size_t)16 * DIM;
    const u16* wg3 = wg0 + (size_t)24 * DIM;

    // prologue: w2 table into LDS (BIAS pre-added)
    {
        float* w2l = (float*)&POOL[73728];
        for (int i = tid; i < SPLIT_CODES; i += 512)
            w2l[i] = w2f[sbase + i] + BIAS;
    }

    uint32 r1[16], r2[16];
    #pragma unroll
    for (int i = 0; i < 16; ++i) { r1[i] = 0xFFFFFFFFu; r2[i] = 0xFFFFFFFFu; }

    f32x4 acc[4][4];
    #pragma unroll
    for (int i = 0; i < 4; ++i)
        #pragma unroll
        for (int c = 0; c < 4; ++c) acc[i][c] = (f32x4){0.f, 0.f, 0.f, 0.f};

    // prologue: stage chunks 0,1 into bufs 0,1 (it=0, kc=0,1)
    #pragma unroll
    for (int tt = 0; tt < 2; ++tt) {
        const int ko = tt * 64;
        gload16(xg0 + ko, &POOL[tt * 8192 + wv * 1024]);
        gload16(xg1 + ko, &POOL[tt * 8192 + wv * 1024 + 512]);
        gload16(wg0 + ko, &POOL[24576 + tt * 16384 + wv * 2048]);
        gload16(wg1 + ko, &POOL[24576 + tt * 16384 + wv * 2048 + 512]);
        gload16(wg2 + ko, &POOL[24576 + tt * 16384 + wv * 2048 + 1024]);
        gload16(wg3 + ko, &POOL[24576 + tt * 16384 + wv * 2048 + 1536]);
    }
    __syncthreads();   // full drain once: w2 table + chunks 0,1 resident

    int bufc = 0;   // buffer of chunk t
    for (int t = 0; t < 64; ++t) {
        // own chunk-t DMAs complete (only chunk t+1's 6 may remain in flight)
        if (t < 63) asm volatile("s_waitcnt vmcnt(6)" ::: "memory");
        else        asm volatile("s_waitcnt vmcnt(0)" ::: "memory");
        __builtin_amdgcn_s_barrier();          // every wave confirmed its slice
        __builtin_amdgcn_sched_barrier(0);     // pin: nothing moves above

        // issue chunk t+2 into buf (bufc+2)%3 == (bufc-1+3)%3
        if (t <= 61) {
            const int bn  = (bufc == 0) ? 2 : bufc - 1;
            const int tn  = t + 2;
            const size_t co = (size_t)(tn >> 3) * (256 * DIM) + (tn & 7) * 64;
            const int ko  = (tn & 7) * 64;
            const size_t xo = (size_t)ko;
            gload16(xg0 + xo, &POOL[bn * 8192 + wv * 1024]);
            gload16(xg1 + xo, &POOL[bn * 8192 + wv * 1024 + 512]);
            gload16(wg0 + co, &POOL[24576 + bn * 16384 + wv * 2048]);
            gload16(wg1 + co, &POOL[24576 + bn * 16384 + wv * 2048 + 512]);
            gload16(wg2 + co, &POOL[24576 + bn * 16384 + wv * 2048 + 1024]);
            gload16(wg3 + co, &POOL[24576 + bn * 16384 + wv * 2048 + 1536]);
        }

        // MFMA on chunk t
        {
            const u16* X = &POOL[bufc * 8192];
            const u16* W = &POOL[24576 + bufc * 16384];
            #pragma unroll
            for (int s = 0; s < 2; ++s) {
                const int lq = s * 4 + quad;
                s16x8 af[4], bf[4];
                #pragma unroll
                for (int i = 0; i < 4; ++i) {
                    const int tr = wt * 64 + i * 16 + n15;      // tr&7 == n15&7
                    af[i] = *(const s16x8*)&X[tr * 64 + (lq ^ (tr & 7)) * 8];
                }
                #pragma unroll
                for (int c = 0; c < 4; ++c) {
                    const int cr = wc * 64 + c * 16 + n15;      // cr&7 == n15&7
                    bf[c] = *(const s16x8*)&W[cr * 64 + (lq ^ (cr & 7)) * 8];
                }
                #pragma unroll
                for (int i = 0; i < 4; ++i)
                    #pragma unroll
                    for (int c = 0; c < 4; ++c)
                        acc[i][c] = __builtin_amdgcn_mfma_f32_16x16x32_bf16(af[i], bf[c], acc[i][c], 0, 0, 0);
            }
        }

        // fold at end of each 256-code column (w2 from LDS: lgkmcnt only)
        if ((t & 7) == 7) {
            const int it = t >> 3;
            const float* w2l = (const float*)&POOL[73728];
            float w2pb[4];
            #pragma unroll
            for (int c = 0; c < 4; ++c)
                w2pb[c] = w2l[it * 256 + wc * 64 + c * 16 + n15];
            #pragma unroll
            for (int i = 0; i < 4; ++i)
                #pragma unroll
                for (int r = 0; r < 4; ++r) {
                    const int ti = i * 4 + r;
                    #pragma unroll
                    for (int c = 0; c < 4; ++c) {
                        float s = fmaf(-2.0f, acc[i][c][r], w2pb[c]);
                        uint32 key = (__float_as_uint(s) & 0xFFFFFFC0u) | (uint32)((it << 2) | c);
                        uint32 mx = r1[ti] > key ? r1[ti] : key;
                        r1[ti] = r1[ti] < key ? r1[ti] : key;
                        r2[ti] = r2[ti] < mx ? r2[ti] : mx;
                    }
                }
            #pragma unroll
            for (int i = 0; i < 4; ++i)
                #pragma unroll
                for (int c = 0; c < 4; ++c) acc[i][c] = (f32x4){0.f, 0.f, 0.f, 0.f};
        }

        bufc = (bufc == 2) ? 0 : bufc + 1;
    }

    // ------- merge: all 128 entries per token via LDS, two phases by wt -----
    u64* MS = (u64*)POOL;   // 64 tokens x 128 entries = 64 KiB
    for (int phase = 0; phase < 2; ++phase) {
        __syncthreads();
        if (wt == phase) {
            #pragma unroll
            for (int ti = 0; ti < 16; ++ti) {
                const int i = ti >> 2, r = ti & 3;
                const int tloc = i * 16 + quad * 4 + r;     // 0..63
                #pragma unroll
                for (int e = 0; e < 2; ++e) {
                    uint32 k  = e ? r2[ti] : r1[ti];
                    uint32 vb = k & 0xFFFFFFC0u;
                    uint32 id = k & 63u;
                    uint32 code = (uint32)(sbase + (id >> 2) * 256 + wc * 64 + (id & 3) * 16 + n15);
                    MS[tloc * 128 + (wc * 16 + n15) * 2 + e] = ((u64)vb << 32) | code;
                }
            }
        }
        __syncthreads();
        if (tid < 64) {
            u64 best[6];
            #pragma unroll
            for (int c = 0; c < 6; ++c) best[c] = 0xFFFFFFFFFFFFFFFFull;
            for (int e = 0; e < 128; ++e) {
                u64 v = MS[tid * 128 + e];
                if (v < best[5]) {
                    best[5] = v;
                    #pragma unroll
                    for (int p = 5; p > 0; --p)
                        if (best[p] < best[p - 1]) { u64 tv = best[p]; best[p] = best[p - 1]; best[p - 1] = tv; }
                }
            }
            const int token = m0 + phase * 64 + tid;
            u64* dst = candPart + ((size_t)blockIdx.y * N_TOK + token) * 6;
            #pragma unroll
            for (int c = 0; c < 6; ++c) dst[c] = best[c];
        }
    }
}

// ---------------------------------------------------------------------------
// Merge per-split top-6 lists -> global top-NCAND candidate codes per token.
// ---------------------------------------------------------------------------
__global__ __launch_bounds__(256) void mergecand_kernel(const u64* __restrict__ candPart,
                                                        int* __restrict__ candF) {
    int t = blockIdx.x * 256 + threadIdx.x;
    u64 best[NCAND];
    #pragma unroll
    for (int c = 0; c < NCAND; ++c) best[c] = 0xFFFFFFFFFFFFFFFFull;
    for (int s = 0; s < NSPLIT; ++s) {
        const u64* src = candPart + ((size_t)s * N_TOK + t) * 6;
        #pragma unroll
        for (int c = 0; c < 6; ++c) {
            u64 v = src[c];
            if (v < best[NCAND - 1]) {
                best[NCAND - 1] = v;
                #pragma unroll
                for (int p = NCAND - 1; p > 0; --p)
                    if (best[p] < best[p - 1]) { u64 tv = best[p]; best[p] = best[p - 1]; best[p - 1] = tv; }
            }
        }
    }
    #pragma unroll
    for (int c = 0; c < NCAND; ++c) candF[(size_t)t * NCAND + c] = (int)(best[c] & 0xFFFu);
}

// ---------------------------------------------------------------------------
// np-exact refine over NCAND candidates (R3-verified arithmetic).
// ---------------------------------------------------------------------------
__global__ __launch_bounds__(256) void refine_kernel(const float* __restrict__ x,
                                                     const float* __restrict__ w,
                                                     const float* __restrict__ x2np,
                                                     const float* __restrict__ w2np,
                                                     const int* __restrict__ cand,
                                                     int* __restrict__ idx) {
    const int t    = blockIdx.x * 4 + (threadIdx.x >> 6);
    const int lane = threadIdx.x & 63;

    const float* xr = x + (size_t)t * DIM;
    float xv[8];
    #pragma unroll
    for (int j = 0; j < 8; ++j) xv[j] = xr[lane + 64 * j];
    const float x2 = x2np[t];

    float bd = 3.4e38f;
    int   bk = 0x7fffffff;
    for (int c = 0; c < NCAND; ++c) {
        int k = cand[(size_t)t * NCAND + c];
        const float* wr = w + (size_t)k * DIM;
        double m = 0.0;
        #pragma unroll
        for (int j = 0; j < 8; ++j)
            m = fma((double)xv[j], (double)wr[lane + 64 * j], m);
        #pragma unroll
        for (int off = 32; off >= 1; off >>= 1) m += __shfl_down(m, off);
        if (lane == 0) {
            #pragma clang fp contract(off)
            float m32 = (float)m;
            float T1  = x2 + w2np[k];
            float d   = T1 - 2.0f * m32;
            if (d < bd || (d == bd && k < bk)) { bd = d; bk = k; }
        }
    }
    if (lane == 0) idx[t] = bk;
}

// ---------------------------------------------------------------------------
// gather + straight-through output + loss + counts (R3-verified).
// ---------------------------------------------------------------------------
__global__ __launch_bounds__(256) void gather_kernel(const float* __restrict__ x,
                                                     const float* __restrict__ w,
                                                     const int* __restrict__ idx,
                                                     float* __restrict__ out_q,
                                                     float* __restrict__ out_loss,
                                                     float* __restrict__ out_ind,
                                                     int* __restrict__ counts) {
    const int wave = threadIdx.x >> 6;
    const int lane = threadIdx.x & 63;
    const int token = blockIdx.x * 4 + wave;
    const int k = idx[token];

    const float4* xr = (const float4*)(x + (size_t)token * DIM);
    const float4* wr = (const float4*)(w + (size_t)k * DIM);
    float4*       qo = (float4*)(out_q + (size_t)token * DIM);

    float ss = 0.f;
    #pragma unroll
    for (int j = 0; j < 2; ++j) {
        int e = lane + j * 64;
        float4 xv = xr[e];
        float4 wv = wr[e];
        float4 d, o;
        d.x = wv.x - xv.x; o.x = xv.x + d.x;
        d.y = wv.y - xv.y; o.y = xv.y + d.y;
        d.z = wv.z - xv.z; o.z = xv.z + d.z;
        d.w = wv.w - xv.w; o.w = xv.w + d.w;
        ss += d.x * d.x + d.y * d.y + d.z * d.z + d.w * d.w;
        qo[e] = o;
    }
    #pragma unroll
    for (int off = 32; off >= 1; off >>= 1) ss += __shfl_down(ss, off);
    if (lane == 0) {
        float lm = ss * (1.0f / DIM);
        out_loss[token] = lm + COMMIT * lm;
        out_ind[token] = (float)k;
        atomicAdd(&counts[k], 1);
    }
}

// ---------------------------------------------------------------------------
// perplexity (R3-verified).
// ---------------------------------------------------------------------------
__global__ __launch_bounds__(256) void perplex_kernel(const int* __restrict__ counts,
                                                      float* __restrict__ out2) {
    __shared__ double red[4];
    const int tid = threadIdx.x;
    const int lane = tid & 63;
    const int wid = tid >> 6;
    double s = 0.0;
    for (int t = tid; t < K_CODES; t += 256) {
        int c = counts[t];
        if (c) {
            double p = (double)c * (1.0 / N_TOK);
            s += p * log(p + 1e-10);
        }
    }
    #pragma unroll
    for (int off = 32; off >= 1; off >>= 1) s += __shfl_down(s, off);
    if (lane == 0) red[wid] = s;
    __syncthreads();
    if (tid == 0) {
        double t = red[0] + red[1] + red[2] + red[3];
        out2[0] = (float)exp(-t);
    }
}

// ---------------------------------------------------------------------------
extern "C" void kernel_launch(void* const* d_in, const int* in_sizes, int n_in,
                              void* d_out, int out_size, void* d_ws, size_t ws_size,
                              hipStream_t stream) {
    const float* x = (const float*)d_in[0];
    const float* w = (const float*)d_in[1];

    float* out0 = (float*)d_out;                       // quantized_st [N,D]
    float* out1 = out0 + (size_t)N_TOK * DIM;          // loss [N]
    float* out2 = out1 + N_TOK;                        // perplexity [1]
    float* out3 = out2 + 1;                            // indices [N] (as float)

    // workspace layout (8B-aligned chunks first)
    u64*   candPart = (u64*)d_ws;                                 // NSPLIT*N_TOK*6
    float* x2np     = (float*)(candPart + (size_t)NSPLIT * N_TOK * 6);
    float* w2np     = x2np + N_TOK;
    int*   idx      = (int*)(w2np + K_CODES);
    int*   counts   = idx + N_TOK;
    int*   candF    = counts + K_CODES;                           // N_TOK*NCAND
    u16*   x_bf     = (u16*)(candF + (size_t)N_TOK * NCAND);      // N_TOK*DIM
    u16*   w_bf     = x_bf + (size_t)N_TOK * DIM;                 // K_CODES*DIM

    hipMemsetAsync(counts, 0, K_CODES * sizeof(int), stream);

    tobf16_kernel<<<4096, 256, 0, stream>>>(x, x_bf, N_TOK * DIM / 4);
    tobf16_kernel<<<2048, 256, 0, stream>>>(w, w_bf, K_CODES * DIM / 4);
    rowsq_np_kernel<<<N_TOK / 32, 256, 0, stream>>>(x, x2np, N_TOK);
    rowsq_np_kernel<<<K_CODES / 32, 256, 0, stream>>>(w, w2np, K_CODES);
    screen_kernel<<<dim3(N_TOK / 128, NSPLIT), 512, 0, stream>>>(x_bf, w_bf, w2np, candPart);
    mergecand_kernel<<<N_TOK / 256, 256, 0, stream>>>(candPart, candF);
    refine_kernel<<<N_TOK / 4, 256, 0, stream>>>(x, w, x2np, w2np, candF, idx);
    gather_kernel<<<N_TOK / 4, 256, 0, stream>>>(x, w, idx, out0, out1, out3, counts);
    perplex_kernel<<<1, 256, 0, stream>>>(counts, out2);
}

// Round 10
// 439.316 us; speedup vs baseline: 1.1617x; 1.0173x over previous
//
#include <hip/hip_runtime.h>
#include <math.h>

#define N_TOK 32768
#define K_CODES 4096
#define DIM 512
#define COMMIT 0.25f
#define NCAND 8
#define NSPLIT 2
#define SPLIT_CODES (K_CODES / NSPLIT)   // 2048
#define NITER (SPLIT_CODES / 256)        // 8 col-iterations of 256 codes
#define BIAS 0.125f

typedef short s16x8 __attribute__((ext_vector_type(8)));
typedef float f32x4 __attribute__((ext_vector_type(4)));
typedef unsigned int uint32;
typedef unsigned long long u64;
typedef unsigned short u16;

__device__ __forceinline__ u16 f2bf(float f) {
    uint32 b = __float_as_uint(f);
    return (u16)((b + 0x7FFFu + ((b >> 16) & 1u)) >> 16);
}

// global -> LDS direct DMA, 16B per lane. LDS dest wave-uniform; HW writes
// lds + lane*16. Source address is per-lane (pre-swizzled).
__device__ __forceinline__ void gload16(const u16* g, u16* l) {
    __builtin_amdgcn_global_load_lds(
        (const __attribute__((address_space(1))) void*)g,
        (__attribute__((address_space(3))) void*)l,
        16, 0, 0);
}

// ---------------------------------------------------------------------------
// fp32 -> bf16 (RNE) bulk convert.
// ---------------------------------------------------------------------------
__global__ __launch_bounds__(256) void tobf16_kernel(const float* __restrict__ src,
                                                     u16* __restrict__ dst, int n4) {
    int i = blockIdx.x * 256 + threadIdx.x;
    int stride = gridDim.x * 256;
    for (; i < n4; i += stride) {
        float4 v = ((const float4*)src)[i];
        ushort4 o;
        o.x = f2bf(v.x); o.y = f2bf(v.y); o.z = f2bf(v.z); o.w = f2bf(v.w);
        ((ushort4*)dst)[i] = o;
    }
}

// ---------------------------------------------------------------------------
// numpy-exact fp32 row sum of squares (pairwise algorithm) — R3-verified.
// ---------------------------------------------------------------------------
__global__ __launch_bounds__(256) void rowsq_np_kernel(const float* __restrict__ a,
                                                       float* __restrict__ out,
                                                       int nrows) {
    #pragma clang fp contract(off)
    const int gw   = (blockIdx.x * 256 + threadIdx.x) >> 6;
    const int lane = threadIdx.x & 63;
    const int row  = gw * 8 + (lane >> 3);
    const int j    = lane & 7;
    if (row >= nrows) return;
    const float* p = a + (size_t)row * DIM;
    float blk[4];
    #pragma unroll
    for (int b = 0; b < 4; ++b) {
        const float* q = p + b * 128;
        float v = q[j];
        float r = v * v;
        for (int i = 8; i < 128; i += 8) { float u = q[i + j]; r += u * u; }
        float s1 = r  + __shfl_xor(r, 1);
        float s2 = s1 + __shfl_xor(s1, 2);
        float s3 = s2 + __shfl_xor(s2, 4);
        blk[b] = s3;
    }
    float res = (blk[0] + blk[1]) + (blk[2] + blk[3]);
    if (j == 0) out[row] = res;
}

// ---------------------------------------------------------------------------
// MFMA bf16 screen — R9 triple-buffer structure + SOFTWARE-PIPELINED LDS
// fragment reads. R2/R4/R9 invariance (226-230 µs across drain/counted/
// fewer-barrier schedules) + VGPR_Count=88 showed the wall is EXPOSED
// ds_read latency: compiler allocates minimal frag regs (self-cap at
// 256/min_waves; (512,2)->128), reads trickle just-in-time, and 2 waves/SIMD
// can't hide ~120cyc LDS latency. Fix: launch_bounds(512,1) lifts the cap to
// 256 (HW still 2 waves/SIMD for <=256 VGPR), and the chunk loop pre-issues
// reads ACROSS the barrier (the one move the compiler can't make):
//   per chunk t: __syncthreads (drains vmcnt -> chunks t,t+1 resident)
//     -> issue DMA t+2 -> issue s1-frag reads of t (hide under s0-MFMAs)
//     -> 16 s0-MFMAs on regs prefetched at t-1
//     -> prefetch s0-frags of chunk t+1 (consumed after next barrier)
//     -> 16 s1-MFMAs.
// Triple buffering makes the cross-barrier prefetch race-free: DMA at t
// targets buf[(t+2)%3]; reads at t touch bufs t%3 and (t+1)%3 only.
// Geometry/semantics identical to R2/R9-verified: 128 tok x 256 codes/iter,
// wave tile 64x64 (acc[4][4]), 128B swizzled rows, top-2 per (lane,ti)
// bucket, id=(it<<2)|c, top-6/split, NCAND=8 np-exact refine.
// ---------------------------------------------------------------------------
__global__ __launch_bounds__(512, 1) void screen_kernel(const u16* __restrict__ xb,
                                                        const u16* __restrict__ wb,
                                                        const float* __restrict__ w2f,
                                                        u64* __restrict__ candPart) {
    __shared__ __attribute__((aligned(16))) u16 POOL[77824];  // 152 KiB
    // u16 offsets: X bufs {0, 8192, 16384} (128 rows x 64 each),
    //              W bufs {24576, 40960, 57344} (256 rows x 64 each),
    //              w2 table @73728 (2048 floats = 8 KiB).
    // Merge phase reuses first 64 KiB as 64 tok x 128 u64.

    const int tid  = threadIdx.x;
    const int wv   = tid >> 6;
    const int wt   = wv >> 2;          // token half (0/1), 64 rows each
    const int wc   = wv & 3;           // code column (0..3), 64 codes each
    const int lane = tid & 63;
    const int quad = lane >> 4;
    const int n15  = lane & 15;
    const int m0   = blockIdx.x * 128;
    const int sbase = blockIdx.y * SPLIT_CODES;

    // DMA geometry: 1 instr = 64 lanes x 16B = 8 rows x 8 quanta (128B rows).
    // phys quantum p at row r holds logical p^(r&7); r&7 == lane>>3 for
    // 8-aligned row bases -> src quantum = (lane&7)^(lane>>3).
    const int l8  = lane >> 3;
    const int qsw = (lane & 7) ^ l8;

    // X: 128 rows, 16 per wave -> 2 instrs.
    const u16* xg0 = xb + (size_t)(m0 + wv * 16 + l8) * DIM + qsw * 8;
    const u16* xg1 = xg0 + (size_t)8 * DIM;
    // W: 256 rows/chunk, 32 per wave -> 4 instrs; chunk (it,kc) adds
    // it*256*DIM + kc*64.
    const u16* wg0 = wb + (size_t)(sbase + wv * 32 + 0  + l8) * DIM + qsw * 8;
    const u16* wg1 = wg0 + (size_t)8 * DIM;
    const u16* wg2 = wg0 + (size_t)16 * DIM;
    const u16* wg3 = wg0 + (size_t)24 * DIM;

    // prologue: w2 table into LDS (BIAS pre-added)
    {
        float* w2l = (float*)&POOL[73728];
        for (int i = tid; i < SPLIT_CODES; i += 512)
            w2l[i] = w2f[sbase + i] + BIAS;
    }

    uint32 r1[16], r2[16];
    #pragma unroll
    for (int i = 0; i < 16; ++i) { r1[i] = 0xFFFFFFFFu; r2[i] = 0xFFFFFFFFu; }

    f32x4 acc[4][4];
    #pragma unroll
    for (int i = 0; i < 4; ++i)
        #pragma unroll
        for (int c = 0; c < 4; ++c) acc[i][c] = (f32x4){0.f, 0.f, 0.f, 0.f};

    // fragment row offsets (loop-invariant per thread, u16 units)
    int xoff0[4], woff0[4], xoff1[4], woff1[4];
    #pragma unroll
    for (int i = 0; i < 4; ++i) {
        const int tr = wt * 64 + i * 16 + n15;
        xoff0[i] = tr * 64 + ((quad)     ^ (tr & 7)) * 8;   // s=0: lq=quad
        xoff1[i] = tr * 64 + ((4 + quad) ^ (tr & 7)) * 8;   // s=1: lq=4+quad
    }
    #pragma unroll
    for (int c = 0; c < 4; ++c) {
        const int cr = wc * 64 + c * 16 + n15;
        woff0[c] = cr * 64 + ((quad)     ^ (cr & 7)) * 8;
        woff1[c] = cr * 64 + ((4 + quad) ^ (cr & 7)) * 8;
    }

    // prologue: stage chunks 0,1 into bufs 0,1 (it=0, kc=0,1)
    #pragma unroll
    for (int tt = 0; tt < 2; ++tt) {
        const int ko = tt * 64;
        gload16(xg0 + ko, &POOL[tt * 8192 + wv * 1024]);
        gload16(xg1 + ko, &POOL[tt * 8192 + wv * 1024 + 512]);
        gload16(wg0 + ko, &POOL[24576 + tt * 16384 + wv * 2048]);
        gload16(wg1 + ko, &POOL[24576 + tt * 16384 + wv * 2048 + 512]);
        gload16(wg2 + ko, &POOL[24576 + tt * 16384 + wv * 2048 + 1024]);
        gload16(wg3 + ko, &POOL[24576 + tt * 16384 + wv * 2048 + 1536]);
    }
    __syncthreads();   // w2 table + chunks 0,1 resident

    // prefetch s0 fragments of chunk 0 (buf 0)
    s16x8 pa[4], pb[4];
    #pragma unroll
    for (int i = 0; i < 4; ++i) pa[i] = *(const s16x8*)&POOL[xoff0[i]];
    #pragma unroll
    for (int c = 0; c < 4; ++c) pb[c] = *(const s16x8*)&POOL[24576 + woff0[c]];

    int bufc = 0;   // buffer of chunk t
    for (int t = 0; t < 64; ++t) {
        __syncthreads();   // drains vmcnt+lgkm: chunks t, t+1 resident in LDS

        // issue DMA chunk t+2 into buf (bufc+2)%3 == (bufc-1+3)%3
        if (t <= 61) {
            const int bn  = (bufc == 0) ? 2 : bufc - 1;
            const int tn  = t + 2;
            const size_t co = (size_t)(tn >> 3) * (256 * DIM) + (tn & 7) * 64;
            const size_t xo = (size_t)((tn & 7) * 64);
            gload16(xg0 + xo, &POOL[bn * 8192 + wv * 1024]);
            gload16(xg1 + xo, &POOL[bn * 8192 + wv * 1024 + 512]);
            gload16(wg0 + co, &POOL[24576 + bn * 16384 + wv * 2048]);
            gload16(wg1 + co, &POOL[24576 + bn * 16384 + wv * 2048 + 512]);
            gload16(wg2 + co, &POOL[24576 + bn * 16384 + wv * 2048 + 1024]);
            gload16(wg3 + co, &POOL[24576 + bn * 16384 + wv * 2048 + 1536]);
        }

        const u16* X = &POOL[bufc * 8192];
        const u16* W = &POOL[24576 + bufc * 16384];

        // issue s1-fragment reads of chunk t (latency hides under s0-MFMAs)
        s16x8 qa[4], qb[4];
        #pragma unroll
        for (int i = 0; i < 4; ++i) qa[i] = *(const s16x8*)&X[xoff1[i]];
        #pragma unroll
        for (int c = 0; c < 4; ++c) qb[c] = *(const s16x8*)&W[woff1[c]];

        // s0 MFMAs on registers prefetched during chunk t-1
        #pragma unroll
        for (int i = 0; i < 4; ++i)
            #pragma unroll
            for (int c = 0; c < 4; ++c)
                acc[i][c] = __builtin_amdgcn_mfma_f32_16x16x32_bf16(pa[i], pb[c], acc[i][c], 0, 0, 0);

        // prefetch s0 fragments of chunk t+1 (consumed after next barrier)
        if (t < 63) {
            const int bn1 = (bufc == 2) ? 0 : bufc + 1;
            const u16* Xn = &POOL[bn1 * 8192];
            const u16* Wn = &POOL[24576 + bn1 * 16384];
            #pragma unroll
            for (int i = 0; i < 4; ++i) pa[i] = *(const s16x8*)&Xn[xoff0[i]];
            #pragma unroll
            for (int c = 0; c < 4; ++c) pb[c] = *(const s16x8*)&Wn[woff0[c]];
        }

        // s1 MFMAs
        #pragma unroll
        for (int i = 0; i < 4; ++i)
            #pragma unroll
            for (int c = 0; c < 4; ++c)
                acc[i][c] = __builtin_amdgcn_mfma_f32_16x16x32_bf16(qa[i], qb[c], acc[i][c], 0, 0, 0);

        // fold at end of each 256-code column (w2 from LDS)
        if ((t & 7) == 7) {
            const int it = t >> 3;
            const float* w2l = (const float*)&POOL[73728];
            float w2pb[4];
            #pragma unroll
            for (int c = 0; c < 4; ++c)
                w2pb[c] = w2l[it * 256 + wc * 64 + c * 16 + n15];
            #pragma unroll
            for (int i = 0; i < 4; ++i)
                #pragma unroll
                for (int r = 0; r < 4; ++r) {
                    const int ti = i * 4 + r;
                    #pragma unroll
                    for (int c = 0; c < 4; ++c) {
                        float s = fmaf(-2.0f, acc[i][c][r], w2pb[c]);
                        uint32 key = (__float_as_uint(s) & 0xFFFFFFC0u) | (uint32)((it << 2) | c);
                        uint32 mx = r1[ti] > key ? r1[ti] : key;
                        r1[ti] = r1[ti] < key ? r1[ti] : key;
                        r2[ti] = r2[ti] < mx ? r2[ti] : mx;
                    }
                }
            #pragma unroll
            for (int i = 0; i < 4; ++i)
                #pragma unroll
                for (int c = 0; c < 4; ++c) acc[i][c] = (f32x4){0.f, 0.f, 0.f, 0.f};
        }

        bufc = (bufc == 2) ? 0 : bufc + 1;
    }

    // ------- merge: all 128 entries per token via LDS, two phases by wt -----
    u64* MS = (u64*)POOL;   // 64 tokens x 128 entries = 64 KiB
    for (int phase = 0; phase < 2; ++phase) {
        __syncthreads();
        if (wt == phase) {
            #pragma unroll
            for (int ti = 0; ti < 16; ++ti) {
                const int i = ti >> 2, r = ti & 3;
                const int tloc = i * 16 + quad * 4 + r;     // 0..63
                #pragma unroll
                for (int e = 0; e < 2; ++e) {
                    uint32 k  = e ? r2[ti] : r1[ti];
                    uint32 vb = k & 0xFFFFFFC0u;
                    uint32 id = k & 63u;
                    uint32 code = (uint32)(sbase + (id >> 2) * 256 + wc * 64 + (id & 3) * 16 + n15);
                    MS[tloc * 128 + (wc * 16 + n15) * 2 + e] = ((u64)vb << 32) | code;
                }
            }
        }
        __syncthreads();
        if (tid < 64) {
            u64 best[6];
            #pragma unroll
            for (int c = 0; c < 6; ++c) best[c] = 0xFFFFFFFFFFFFFFFFull;
            for (int e = 0; e < 128; ++e) {
                u64 v = MS[tid * 128 + e];
                if (v < best[5]) {
                    best[5] = v;
                    #pragma unroll
                    for (int p = 5; p > 0; --p)
                        if (best[p] < best[p - 1]) { u64 tv = best[p]; best[p] = best[p - 1]; best[p - 1] = tv; }
                }
            }
            const int token = m0 + phase * 64 + tid;
            u64* dst = candPart + ((size_t)blockIdx.y * N_TOK + token) * 6;
            #pragma unroll
            for (int c = 0; c < 6; ++c) dst[c] = best[c];
        }
    }
}

// ---------------------------------------------------------------------------
// Merge per-split top-6 lists -> global top-NCAND candidate codes per token.
// ---------------------------------------------------------------------------
__global__ __launch_bounds__(256) void mergecand_kernel(const u64* __restrict__ candPart,
                                                        int* __restrict__ candF) {
    int t = blockIdx.x * 256 + threadIdx.x;
    u64 best[NCAND];
    #pragma unroll
    for (int c = 0; c < NCAND; ++c) best[c] = 0xFFFFFFFFFFFFFFFFull;
    for (int s = 0; s < NSPLIT; ++s) {
        const u64* src = candPart + ((size_t)s * N_TOK + t) * 6;
        #pragma unroll
        for (int c = 0; c < 6; ++c) {
            u64 v = src[c];
            if (v < best[NCAND - 1]) {
                best[NCAND - 1] = v;
                #pragma unroll
                for (int p = NCAND - 1; p > 0; --p)
                    if (best[p] < best[p - 1]) { u64 tv = best[p]; best[p] = best[p - 1]; best[p - 1] = tv; }
            }
        }
    }
    #pragma unroll
    for (int c = 0; c < NCAND; ++c) candF[(size_t)t * NCAND + c] = (int)(best[c] & 0xFFFu);
}

// ---------------------------------------------------------------------------
// np-exact refine over NCAND candidates (R3-verified arithmetic).
// ---------------------------------------------------------------------------
__global__ __launch_bounds__(256) void refine_kernel(const float* __restrict__ x,
                                                     const float* __restrict__ w,
                                                     const float* __restrict__ x2np,
                                                     const float* __restrict__ w2np,
                                                     const int* __restrict__ cand,
                                                     int* __restrict__ idx) {
    const int t    = blockIdx.x * 4 + (threadIdx.x >> 6);
    const int lane = threadIdx.x & 63;

    const float* xr = x + (size_t)t * DIM;
    float xv[8];
    #pragma unroll
    for (int j = 0; j < 8; ++j) xv[j] = xr[lane + 64 * j];
    const float x2 = x2np[t];

    float bd = 3.4e38f;
    int   bk = 0x7fffffff;
    for (int c = 0; c < NCAND; ++c) {
        int k = cand[(size_t)t * NCAND + c];
        const float* wr = w + (size_t)k * DIM;
        double m = 0.0;
        #pragma unroll
        for (int j = 0; j < 8; ++j)
            m = fma((double)xv[j], (double)wr[lane + 64 * j], m);
        #pragma unroll
        for (int off = 32; off >= 1; off >>= 1) m += __shfl_down(m, off);
        if (lane == 0) {
            #pragma clang fp contract(off)
            float m32 = (float)m;
            float T1  = x2 + w2np[k];
            float d   = T1 - 2.0f * m32;
            if (d < bd || (d == bd && k < bk)) { bd = d; bk = k; }
        }
    }
    if (lane == 0) idx[t] = bk;
}

// ---------------------------------------------------------------------------
// gather + straight-through output + loss + counts (R3-verified).
// ---------------------------------------------------------------------------
__global__ __launch_bounds__(256) void gather_kernel(const float* __restrict__ x,
                                                     const float* __restrict__ w,
                                                     const int* __restrict__ idx,
                                                     float* __restrict__ out_q,
                                                     float* __restrict__ out_loss,
                                                     float* __restrict__ out_ind,
                                                     int* __restrict__ counts) {
    const int wave = threadIdx.x >> 6;
    const int lane = threadIdx.x & 63;
    const int token = blockIdx.x * 4 + wave;
    const int k = idx[token];

    const float4* xr = (const float4*)(x + (size_t)token * DIM);
    const float4* wr = (const float4*)(w + (size_t)k * DIM);
    float4*       qo = (float4*)(out_q + (size_t)token * DIM);

    float ss = 0.f;
    #pragma unroll
    for (int j = 0; j < 2; ++j) {
        int e = lane + j * 64;
        float4 xv = xr[e];
        float4 wv = wr[e];
        float4 d, o;
        d.x = wv.x - xv.x; o.x = xv.x + d.x;
        d.y = wv.y - xv.y; o.y = xv.y + d.y;
        d.z = wv.z - xv.z; o.z = xv.z + d.z;
        d.w = wv.w - xv.w; o.w = xv.w + d.w;
        ss += d.x * d.x + d.y * d.y + d.z * d.z + d.w * d.w;
        qo[e] = o;
    }
    #pragma unroll
    for (int off = 32; off >= 1; off >>= 1) ss += __shfl_down(ss, off);
    if (lane == 0) {
        float lm = ss * (1.0f / DIM);
        out_loss[token] = lm + COMMIT * lm;
        out_ind[token] = (float)k;
        atomicAdd(&counts[k], 1);
    }
}

// ---------------------------------------------------------------------------
// perplexity (R3-verified).
// ---------------------------------------------------------------------------
__global__ __launch_bounds__(256) void perplex_kernel(const int* __restrict__ counts,
                                                      float* __restrict__ out2) {
    __shared__ double red[4];
    const int tid = threadIdx.x;
    const int lane = tid & 63;
    const int wid = tid >> 6;
    double s = 0.0;
    for (int t = tid; t < K_CODES; t += 256) {
        int c = counts[t];
        if (c) {
            double p = (double)c * (1.0 / N_TOK);
            s += p * log(p + 1e-10);
        }
    }
    #pragma unroll
    for (int off = 32; off >= 1; off >>= 1) s += __shfl_down(s, off);
    if (lane == 0) red[wid] = s;
    __syncthreads();
    if (tid == 0) {
        double t = red[0] + red[1] + red[2] + red[3];
        out2[0] = (float)exp(-t);
    }
}

// ---------------------------------------------------------------------------
extern "C" void kernel_launch(void* const* d_in, const int* in_sizes, int n_in,
                              void* d_out, int out_size, void* d_ws, size_t ws_size,
                              hipStream_t stream) {
    const float* x = (const float*)d_in[0];
    const float* w = (const float*)d_in[1];

    float* out0 = (float*)d_out;                       // quantized_st [N,D]
    float* out1 = out0 + (size_t)N_TOK * DIM;          // loss [N]
    float* out2 = out1 + N_TOK;                        // perplexity [1]
    float* out3 = out2 + 1;                            // indices [N] (as float)

    // workspace layout (8B-aligned chunks first)
    u64*   candPart = (u64*)d_ws;                                 // NSPLIT*N_TOK*6
    float* x2np     = (float*)(candPart + (size_t)NSPLIT * N_TOK * 6);
    float* w2np     = x2np + N_TOK;
    int*   idx      = (int*)(w2np + K_CODES);
    int*   counts   = idx + N_TOK;
    int*   candF    = counts + K_CODES;                           // N_TOK*NCAND
    u16*   x_bf     = (u16*)(candF + (size_t)N_TOK * NCAND);      // N_TOK*DIM
    u16*   w_bf     = x_bf + (size_t)N_TOK * DIM;                 // K_CODES*DIM

    hipMemsetAsync(counts, 0, K_CODES * sizeof(int), stream);

    tobf16_kernel<<<4096, 256, 0, stream>>>(x, x_bf, N_TOK * DIM / 4);
    tobf16_kernel<<<2048, 256, 0, stream>>>(w, w_bf, K_CODES * DIM / 4);
    rowsq_np_kernel<<<N_TOK / 32, 256, 0, stream>>>(x, x2np, N_TOK);
    rowsq_np_kernel<<<K_CODES / 32, 256, 0, stream>>>(w, w2np, K_CODES);
    screen_kernel<<<dim3(N_TOK / 128, NSPLIT), 512, 0, stream>>>(x_bf, w_bf, w2np, candPart);
    mergecand_kernel<<<N_TOK / 256, 256, 0, stream>>>(candPart, candF);
    refine_kernel<<<N_TOK / 4, 256, 0, stream>>>(x, w, x2np, w2np, candF, idx);
    gather_kernel<<<N_TOK / 4, 256, 0, stream>>>(x, w, idx, out0, out1, out3, counts);
    perplex_kernel<<<1, 256, 0, stream>>>(counts, out2);
}

// Round 11
// 425.037 us; speedup vs baseline: 1.2007x; 1.0336x over previous
//
#include <hip/hip_runtime.h>
#include <math.h>

#define N_TOK 32768
#define K_CODES 4096
#define DIM 512
#define COMMIT 0.25f
#define NCAND 8
#define NSPLIT 2
#define SPLIT_CODES (K_CODES / NSPLIT)   // 2048
#define NITER (SPLIT_CODES / 256)        // 8 col-iterations of 256 codes
#define BIAS 0.125f

typedef short s16x8 __attribute__((ext_vector_type(8)));
typedef float f32x4 __attribute__((ext_vector_type(4)));
typedef unsigned int uint32;
typedef unsigned long long u64;
typedef unsigned short u16;

__device__ __forceinline__ u16 f2bf(float f) {
    uint32 b = __float_as_uint(f);
    return (u16)((b + 0x7FFFu + ((b >> 16) & 1u)) >> 16);
}

// global -> LDS direct DMA, 16B per lane. LDS dest wave-uniform; HW writes
// lds + lane*16. Source address is per-lane (pre-swizzled).
__device__ __forceinline__ void gload16(const u16* g, u16* l) {
    __builtin_amdgcn_global_load_lds(
        (const __attribute__((address_space(1))) void*)g,
        (__attribute__((address_space(3))) void*)l,
        16, 0, 0);
}

// ---------------------------------------------------------------------------
// FUSED prep: fp32->bf16 (RNE) + numpy-exact pairwise row sum-of-squares.
// One block = 32 rows (4 waves x 8 rows). bf16 pass uses float4 loads; the
// rowsq pass re-reads the same 32 rows scalar (L1/L2-hot). rowsq arithmetic
// is character-identical to the R3-verified rowsq_np_kernel.
// ---------------------------------------------------------------------------
__global__ __launch_bounds__(256) void prep_kernel(const float* __restrict__ src,
                                                   u16* __restrict__ bf,
                                                   float* __restrict__ sq) {
    #pragma clang fp contract(off)
    const int tid  = threadIdx.x;
    const int row0 = blockIdx.x * 32;

    // part 1: bf16 convert 32 rows = 4096 float4 (16 per thread)
    {
        const float4* s4 = (const float4*)src + (size_t)row0 * 128;
        ushort4*      d4 = (ushort4*)bf + (size_t)row0 * 128;
        #pragma unroll
        for (int i = 0; i < 16; ++i) {
            int e = tid + i * 256;
            float4 v = s4[e];
            ushort4 o;
            o.x = f2bf(v.x); o.y = f2bf(v.y); o.z = f2bf(v.z); o.w = f2bf(v.w);
            d4[e] = o;
        }
    }

    // part 2: numpy-exact rowsq (identical ops/order to rowsq_np_kernel)
    const int lane = tid & 63;
    const int wvi  = tid >> 6;
    const int row  = row0 + wvi * 8 + (lane >> 3);
    const int j    = lane & 7;
    const float* p = src + (size_t)row * DIM;
    float blk[4];
    #pragma unroll
    for (int b = 0; b < 4; ++b) {
        const float* q = p + b * 128;
        float v = q[j];
        float r = v * v;
        for (int i = 8; i < 128; i += 8) { float u = q[i + j]; r += u * u; }
        float s1 = r  + __shfl_xor(r, 1);
        float s2 = s1 + __shfl_xor(s1, 2);
        float s3 = s2 + __shfl_xor(s2, 4);
        blk[b] = s3;
    }
    float res = (blk[0] + blk[1]) + (blk[2] + blk[3]);
    if (j == 0) sq[row] = res;
}

// ---------------------------------------------------------------------------
// MFMA bf16 screen — R10-verified (212.5 µs), byte-identical this round.
// R9 triple-buffer + software-pipelined LDS fragment reads across barriers.
// 128 tok x 256 codes/iter, wave tile 64x64 (acc[4][4]), 128B swizzled rows,
// top-2 per (lane,ti) bucket, id=(it<<2)|c, top-6/split.
// ---------------------------------------------------------------------------
__global__ __launch_bounds__(512, 1) void screen_kernel(const u16* __restrict__ xb,
                                                        const u16* __restrict__ wb,
                                                        const float* __restrict__ w2f,
                                                        u64* __restrict__ candPart) {
    __shared__ __attribute__((aligned(16))) u16 POOL[77824];  // 152 KiB
    // u16 offsets: X bufs {0, 8192, 16384} (128 rows x 64 each),
    //              W bufs {24576, 40960, 57344} (256 rows x 64 each),
    //              w2 table @73728 (2048 floats = 8 KiB).
    // Merge phase reuses first 64 KiB as 64 tok x 128 u64.

    const int tid  = threadIdx.x;
    const int wv   = tid >> 6;
    const int wt   = wv >> 2;          // token half (0/1), 64 rows each
    const int wc   = wv & 3;           // code column (0..3), 64 codes each
    const int lane = tid & 63;
    const int quad = lane >> 4;
    const int n15  = lane & 15;
    const int m0   = blockIdx.x * 128;
    const int sbase = blockIdx.y * SPLIT_CODES;

    const int l8  = lane >> 3;
    const int qsw = (lane & 7) ^ l8;

    const u16* xg0 = xb + (size_t)(m0 + wv * 16 + l8) * DIM + qsw * 8;
    const u16* xg1 = xg0 + (size_t)8 * DIM;
    const u16* wg0 = wb + (size_t)(sbase + wv * 32 + 0  + l8) * DIM + qsw * 8;
    const u16* wg1 = wg0 + (size_t)8 * DIM;
    const u16* wg2 = wg0 + (size_t)16 * DIM;
    const u16* wg3 = wg0 + (size_t)24 * DIM;

    // prologue: w2 table into LDS (BIAS pre-added)
    {
        float* w2l = (float*)&POOL[73728];
        for (int i = tid; i < SPLIT_CODES; i += 512)
            w2l[i] = w2f[sbase + i] + BIAS;
    }

    uint32 r1[16], r2[16];
    #pragma unroll
    for (int i = 0; i < 16; ++i) { r1[i] = 0xFFFFFFFFu; r2[i] = 0xFFFFFFFFu; }

    f32x4 acc[4][4];
    #pragma unroll
    for (int i = 0; i < 4; ++i)
        #pragma unroll
        for (int c = 0; c < 4; ++c) acc[i][c] = (f32x4){0.f, 0.f, 0.f, 0.f};

    int xoff0[4], woff0[4], xoff1[4], woff1[4];
    #pragma unroll
    for (int i = 0; i < 4; ++i) {
        const int tr = wt * 64 + i * 16 + n15;
        xoff0[i] = tr * 64 + ((quad)     ^ (tr & 7)) * 8;
        xoff1[i] = tr * 64 + ((4 + quad) ^ (tr & 7)) * 8;
    }
    #pragma unroll
    for (int c = 0; c < 4; ++c) {
        const int cr = wc * 64 + c * 16 + n15;
        woff0[c] = cr * 64 + ((quad)     ^ (cr & 7)) * 8;
        woff1[c] = cr * 64 + ((4 + quad) ^ (cr & 7)) * 8;
    }

    #pragma unroll
    for (int tt = 0; tt < 2; ++tt) {
        const int ko = tt * 64;
        gload16(xg0 + ko, &POOL[tt * 8192 + wv * 1024]);
        gload16(xg1 + ko, &POOL[tt * 8192 + wv * 1024 + 512]);
        gload16(wg0 + ko, &POOL[24576 + tt * 16384 + wv * 2048]);
        gload16(wg1 + ko, &POOL[24576 + tt * 16384 + wv * 2048 + 512]);
        gload16(wg2 + ko, &POOL[24576 + tt * 16384 + wv * 2048 + 1024]);
        gload16(wg3 + ko, &POOL[24576 + tt * 16384 + wv * 2048 + 1536]);
    }
    __syncthreads();   // w2 table + chunks 0,1 resident

    // prefetch s0 fragments of chunk 0 (buf 0)
    s16x8 pa[4], pb[4];
    #pragma unroll
    for (int i = 0; i < 4; ++i) pa[i] = *(const s16x8*)&POOL[xoff0[i]];
    #pragma unroll
    for (int c = 0; c < 4; ++c) pb[c] = *(const s16x8*)&POOL[24576 + woff0[c]];

    int bufc = 0;
    for (int t = 0; t < 64; ++t) {
        __syncthreads();   // chunks t, t+1 resident in LDS

        if (t <= 61) {
            const int bn  = (bufc == 0) ? 2 : bufc - 1;
            const int tn  = t + 2;
            const size_t co = (size_t)(tn >> 3) * (256 * DIM) + (tn & 7) * 64;
            const size_t xo = (size_t)((tn & 7) * 64);
            gload16(xg0 + xo, &POOL[bn * 8192 + wv * 1024]);
            gload16(xg1 + xo, &POOL[bn * 8192 + wv * 1024 + 512]);
            gload16(wg0 + co, &POOL[24576 + bn * 16384 + wv * 2048]);
            gload16(wg1 + co, &POOL[24576 + bn * 16384 + wv * 2048 + 512]);
            gload16(wg2 + co, &POOL[24576 + bn * 16384 + wv * 2048 + 1024]);
            gload16(wg3 + co, &POOL[24576 + bn * 16384 + wv * 2048 + 1536]);
        }

        const u16* X = &POOL[bufc * 8192];
        const u16* W = &POOL[24576 + bufc * 16384];

        // issue s1-fragment reads of chunk t (hide under s0-MFMAs)
        s16x8 qa[4], qb[4];
        #pragma unroll
        for (int i = 0; i < 4; ++i) qa[i] = *(const s16x8*)&X[xoff1[i]];
        #pragma unroll
        for (int c = 0; c < 4; ++c) qb[c] = *(const s16x8*)&W[woff1[c]];

        // s0 MFMAs on registers prefetched during chunk t-1
        #pragma unroll
        for (int i = 0; i < 4; ++i)
            #pragma unroll
            for (int c = 0; c < 4; ++c)
                acc[i][c] = __builtin_amdgcn_mfma_f32_16x16x32_bf16(pa[i], pb[c], acc[i][c], 0, 0, 0);

        // prefetch s0 fragments of chunk t+1 (consumed after next barrier)
        if (t < 63) {
            const int bn1 = (bufc == 2) ? 0 : bufc + 1;
            const u16* Xn = &POOL[bn1 * 8192];
            const u16* Wn = &POOL[24576 + bn1 * 16384];
            #pragma unroll
            for (int i = 0; i < 4; ++i) pa[i] = *(const s16x8*)&Xn[xoff0[i]];
            #pragma unroll
            for (int c = 0; c < 4; ++c) pb[c] = *(const s16x8*)&Wn[woff0[c]];
        }

        // s1 MFMAs
        #pragma unroll
        for (int i = 0; i < 4; ++i)
            #pragma unroll
            for (int c = 0; c < 4; ++c)
                acc[i][c] = __builtin_amdgcn_mfma_f32_16x16x32_bf16(qa[i], qb[c], acc[i][c], 0, 0, 0);

        // fold at end of each 256-code column (w2 from LDS)
        if ((t & 7) == 7) {
            const int it = t >> 3;
            const float* w2l = (const float*)&POOL[73728];
            float w2pb[4];
            #pragma unroll
            for (int c = 0; c < 4; ++c)
                w2pb[c] = w2l[it * 256 + wc * 64 + c * 16 + n15];
            #pragma unroll
            for (int i = 0; i < 4; ++i)
                #pragma unroll
                for (int r = 0; r < 4; ++r) {
                    const int ti = i * 4 + r;
                    #pragma unroll
                    for (int c = 0; c < 4; ++c) {
                        float s = fmaf(-2.0f, acc[i][c][r], w2pb[c]);
                        uint32 key = (__float_as_uint(s) & 0xFFFFFFC0u) | (uint32)((it << 2) | c);
                        uint32 mx = r1[ti] > key ? r1[ti] : key;
                        r1[ti] = r1[ti] < key ? r1[ti] : key;
                        r2[ti] = r2[ti] < mx ? r2[ti] : mx;
                    }
                }
            #pragma unroll
            for (int i = 0; i < 4; ++i)
                #pragma unroll
                for (int c = 0; c < 4; ++c) acc[i][c] = (f32x4){0.f, 0.f, 0.f, 0.f};
        }

        bufc = (bufc == 2) ? 0 : bufc + 1;
    }

    // ------- merge: all 128 entries per token via LDS, two phases by wt -----
    u64* MS = (u64*)POOL;   // 64 tokens x 128 entries = 64 KiB
    for (int phase = 0; phase < 2; ++phase) {
        __syncthreads();
        if (wt == phase) {
            #pragma unroll
            for (int ti = 0; ti < 16; ++ti) {
                const int i = ti >> 2, r = ti & 3;
                const int tloc = i * 16 + quad * 4 + r;     // 0..63
                #pragma unroll
                for (int e = 0; e < 2; ++e) {
                    uint32 k  = e ? r2[ti] : r1[ti];
                    uint32 vb = k & 0xFFFFFFC0u;
                    uint32 id = k & 63u;
                    uint32 code = (uint32)(sbase + (id >> 2) * 256 + wc * 64 + (id & 3) * 16 + n15);
                    MS[tloc * 128 + (wc * 16 + n15) * 2 + e] = ((u64)vb << 32) | code;
                }
            }
        }
        __syncthreads();
        if (tid < 64) {
            u64 best[6];
            #pragma unroll
            for (int c = 0; c < 6; ++c) best[c] = 0xFFFFFFFFFFFFFFFFull;
            for (int e = 0; e < 128; ++e) {
                u64 v = MS[tid * 128 + e];
                if (v < best[5]) {
                    best[5] = v;
                    #pragma unroll
                    for (int p = 5; p > 0; --p)
                        if (best[p] < best[p - 1]) { u64 tv = best[p]; best[p] = best[p - 1]; best[p - 1] = tv; }
                }
            }
            const int token = m0 + phase * 64 + tid;
            u64* dst = candPart + ((size_t)blockIdx.y * N_TOK + token) * 6;
            #pragma unroll
            for (int c = 0; c < 6; ++c) dst[c] = best[c];
        }
    }
}

// ---------------------------------------------------------------------------
// FUSED mergecand + np-exact refine + gather/loss/counts. One wave = one
// token. Merge order and all arithmetic identical to the verified split
// kernels (same insertion sort -> same candidate order -> same tie-breaks;
// refine dot in fp64 with fp-contract-off final compare; gather math
// unchanged). Winner broadcast via __shfl(bk, 0).
// ---------------------------------------------------------------------------
__global__ __launch_bounds__(256) void refine_gather_kernel(
        const float* __restrict__ x, const float* __restrict__ w,
        const float* __restrict__ x2np, const float* __restrict__ w2np,
        const u64* __restrict__ candPart,
        float* __restrict__ out_q, float* __restrict__ out_loss,
        float* __restrict__ out_ind, int* __restrict__ counts) {
    const int t    = blockIdx.x * 4 + (threadIdx.x >> 6);
    const int lane = threadIdx.x & 63;

    // merge NSPLIT x top-6 -> top-NCAND (identical to mergecand_kernel;
    // every lane computes the same list — same-address loads broadcast)
    u64 best[NCAND];
    #pragma unroll
    for (int c = 0; c < NCAND; ++c) best[c] = 0xFFFFFFFFFFFFFFFFull;
    #pragma unroll
    for (int s = 0; s < NSPLIT; ++s) {
        const u64* src = candPart + ((size_t)s * N_TOK + t) * 6;
        #pragma unroll
        for (int c = 0; c < 6; ++c) {
            u64 v = src[c];
            if (v < best[NCAND - 1]) {
                best[NCAND - 1] = v;
                #pragma unroll
                for (int p = NCAND - 1; p > 0; --p)
                    if (best[p] < best[p - 1]) { u64 tv = best[p]; best[p] = best[p - 1]; best[p - 1] = tv; }
            }
        }
    }

    // refine (identical arithmetic to refine_kernel)
    const float* xr = x + (size_t)t * DIM;
    float xv[8];
    #pragma unroll
    for (int j = 0; j < 8; ++j) xv[j] = xr[lane + 64 * j];
    const float x2 = x2np[t];

    float bd = 3.4e38f;
    int   bk = 0x7fffffff;
    for (int c = 0; c < NCAND; ++c) {
        int k = (int)(best[c] & 0xFFFu);
        const float* wr = w + (size_t)k * DIM;
        double m = 0.0;
        #pragma unroll
        for (int j = 0; j < 8; ++j)
            m = fma((double)xv[j], (double)wr[lane + 64 * j], m);
        #pragma unroll
        for (int off = 32; off >= 1; off >>= 1) m += __shfl_down(m, off);
        if (lane == 0) {
            #pragma clang fp contract(off)
            float m32 = (float)m;
            float T1  = x2 + w2np[k];
            float d   = T1 - 2.0f * m32;
            if (d < bd || (d == bd && k < bk)) { bd = d; bk = k; }
        }
    }
    const int kk = __shfl(bk, 0);   // lane0's winner

    // gather + straight-through + loss + counts (identical to gather_kernel)
    const float4* xr4 = (const float4*)(x + (size_t)t * DIM);
    const float4* wr4 = (const float4*)(w + (size_t)kk * DIM);
    float4*       qo  = (float4*)(out_q + (size_t)t * DIM);

    float ss = 0.f;
    #pragma unroll
    for (int j = 0; j < 2; ++j) {
        int e = lane + j * 64;
        float4 xv4 = xr4[e];
        float4 wv4 = wr4[e];
        float4 d, o;
        d.x = wv4.x - xv4.x; o.x = xv4.x + d.x;
        d.y = wv4.y - xv4.y; o.y = xv4.y + d.y;
        d.z = wv4.z - xv4.z; o.z = xv4.z + d.z;
        d.w = wv4.w - xv4.w; o.w = xv4.w + d.w;
        ss += d.x * d.x + d.y * d.y + d.z * d.z + d.w * d.w;
        qo[e] = o;
    }
    #pragma unroll
    for (int off = 32; off >= 1; off >>= 1) ss += __shfl_down(ss, off);
    if (lane == 0) {
        float lm = ss * (1.0f / DIM);
        out_loss[t] = lm + COMMIT * lm;
        out_ind[t] = (float)kk;
        atomicAdd(&counts[kk], 1);
    }
}

// ---------------------------------------------------------------------------
// perplexity (R3-verified).
// ---------------------------------------------------------------------------
__global__ __launch_bounds__(256) void perplex_kernel(const int* __restrict__ counts,
                                                      float* __restrict__ out2) {
    __shared__ double red[4];
    const int tid = threadIdx.x;
    const int lane = tid & 63;
    const int wid = tid >> 6;
    double s = 0.0;
    for (int t = tid; t < K_CODES; t += 256) {
        int c = counts[t];
        if (c) {
            double p = (double)c * (1.0 / N_TOK);
            s += p * log(p + 1e-10);
        }
    }
    #pragma unroll
    for (int off = 32; off >= 1; off >>= 1) s += __shfl_down(s, off);
    if (lane == 0) red[wid] = s;
    __syncthreads();
    if (tid == 0) {
        double t = red[0] + red[1] + red[2] + red[3];
        out2[0] = (float)exp(-t);
    }
}

// ---------------------------------------------------------------------------
extern "C" void kernel_launch(void* const* d_in, const int* in_sizes, int n_in,
                              void* d_out, int out_size, void* d_ws, size_t ws_size,
                              hipStream_t stream) {
    const float* x = (const float*)d_in[0];
    const float* w = (const float*)d_in[1];

    float* out0 = (float*)d_out;                       // quantized_st [N,D]
    float* out1 = out0 + (size_t)N_TOK * DIM;          // loss [N]
    float* out2 = out1 + N_TOK;                        // perplexity [1]
    float* out3 = out2 + 1;                            // indices [N] (as float)

    // workspace layout (8B-aligned chunks first)
    u64*   candPart = (u64*)d_ws;                                 // NSPLIT*N_TOK*6
    float* x2np     = (float*)(candPart + (size_t)NSPLIT * N_TOK * 6);
    float* w2np     = x2np + N_TOK;
    int*   idx      = (int*)(w2np + K_CODES);
    int*   counts   = idx + N_TOK;
    int*   candF    = counts + K_CODES;                           // (unused now)
    u16*   x_bf     = (u16*)(candF + (size_t)N_TOK * NCAND);      // N_TOK*DIM
    u16*   w_bf     = x_bf + (size_t)N_TOK * DIM;                 // K_CODES*DIM

    hipMemsetAsync(counts, 0, K_CODES * sizeof(int), stream);

    prep_kernel<<<N_TOK / 32, 256, 0, stream>>>(x, x_bf, x2np);
    prep_kernel<<<K_CODES / 32, 256, 0, stream>>>(w, w_bf, w2np);
    screen_kernel<<<dim3(N_TOK / 128, NSPLIT), 512, 0, stream>>>(x_bf, w_bf, w2np, candPart);
    refine_gather_kernel<<<N_TOK / 4, 256, 0, stream>>>(x, w, x2np, w2np, candPart,
                                                        out0, out1, out3, counts);
    perplex_kernel<<<1, 256, 0, stream>>>(counts, out2);
}